// Round 5
// baseline (113.338 us; speedup 1.0000x reference)
//
#include <hip/hip_runtime.h>
#include <hip/hip_fp16.h>

#define BB 4
#define NN 8192
#define DD 256
#define HH 8
#define MM 32768   // BB*NN

typedef __attribute__((ext_vector_type(8))) _Float16 half8;
typedef __attribute__((ext_vector_type(4))) _Float16 half4;
typedef __attribute__((ext_vector_type(4))) float f32x4;

#define GLL(src, dst)                                                        \
  __builtin_amdgcn_global_load_lds(                                          \
      (const __attribute__((address_space(1))) void*)(src),                  \
      (__attribute__((address_space(3))) void*)(dst), 16, 0, 0)

// ---------------- K0: W conversion ----------------
// W_qkv [256][1536] fp32 -> Wt [1536][256] fp16 (transposed)
__global__ void __launch_bounds__(256) k_cvt_w(const float* __restrict__ w,
                                               _Float16* __restrict__ wt) {
  int idx = blockIdx.x * 256 + threadIdx.x;  // 0..393215
  int k = idx / 1536, c = idx % 1536;
  wt[(size_t)c * 256 + k] = (_Float16)w[idx];
}

// ---------------- K1: qkv GEMM + norm + rotary + fused dots-partial ----------------
// grid(512): 64 rows x 1536 cols, K=256. 4 waves. x-fragments held in REGISTERS
// (af reused across all 8 heads); LDS = W double-buffer only (48 KB -> 3 blocks/CU).
__global__ void __launch_bounds__(256, 3) k_qkv(const float* __restrict__ x,
                                                const _Float16* __restrict__ wt,
                                                const float* __restrict__ pos,
                                                _Float16* __restrict__ q16,
                                                _Float16* __restrict__ part16) {
  __shared__ alignas(16) _Float16 wb[2][12288];   // [192 cols][64 K] swizzled, 24 KB x2
  const int row0 = blockIdx.x * 64;
  const int t = threadIdx.x;
  const int wv = t >> 6, l = t & 63, lr = l & 15, lg = l >> 4;
  const int myrow = row0 + wv * 16 + lr;

  // ---- x fragments: direct coalesced global loads, fp32 -> fp16, held in regs ----
  half8 afr[8];
#pragma unroll
  for (int c = 0; c < 8; ++c) {      // c = kt*2 + sp
    const float* src = x + (size_t)myrow * 256 + c * 32 + lg * 8;
    float4 a = *(const float4*)src;
    float4 b = *(const float4*)(src + 4);
    half8 hv;
    hv[0] = (_Float16)a.x; hv[1] = (_Float16)a.y; hv[2] = (_Float16)a.z; hv[3] = (_Float16)a.w;
    hv[4] = (_Float16)b.x; hv[5] = (_Float16)b.y; hv[6] = (_Float16)b.z; hv[7] = (_Float16)b.w;
    afr[c] = hv;
  }

  // ---- hoist rotary angles: freq index = lg*4+j ----
  const float px = pos[(size_t)myrow * 2 + 0] * 64.0f;
  const float py = pos[(size_t)myrow * 2 + 1] * 64.0f;
  float sxj[4], cxj[4], syj[4], cyj[4];
#pragma unroll
  for (int j = 0; j < 4; ++j) {
    float invf = exp2f((float)(lg * 4 + j) * -0.8304820237218405f);  // 10000^(-fi/16)
    __sincosf(px * invf, &sxj[j], &cxj[j]);
    __sincosf(py * invf, &syj[j], &cyj[j]);
  }

  // ---- W staging: global_load_lds, pre-swizzled source ----
  auto stageW = [&](int buf, int hh, int kt) {
#pragma unroll
    for (int call = 0; call < 6; ++call) {
      int ob = (call * 4 + wv) * 1024;             // wave-uniform dest base (bytes)
      int o = ob + l * 16;                         // this lane's dest byte
      int c = o >> 7;                              // col 0..191
      int kb = (o & 127) ^ ((c & 7) << 4);         // logical K byte
      int gc = ((c >> 6) << 9) + (hh << 6) + (c & 63);  // global wt row
      const char* src = (const char*)(wt + (size_t)gc * 256 + kt * 64) + kb;
      GLL(src, (char*)&wb[buf][0] + ob);
    }
  };

  stageW(0, 0, 0);
  __syncthreads();

  int cur = 0;
#pragma unroll 1
  for (int h = 0; h < 8; ++h) {
    f32x4 acc[12] = {};
#pragma unroll 1
    for (int kt = 0; kt < 4; ++kt) {
      int ni = (h << 2) + kt + 1;
      if (ni < 32) stageW(cur ^ 1, ni >> 2, ni & 3);
      const char* wbp = (const char*)&wb[cur][0];
#pragma unroll
      for (int sp = 0; sp < 2; ++sp) {
        half8 af = afr[kt * 2 + sp];
        int wkb = sp * 64 + lg * 16;
#pragma unroll
        for (int cf = 0; cf < 12; ++cf) {
          int c = cf * 16 + lr;
          half8 bf = *(const half8*)(wbp + c * 128 + (wkb ^ ((c & 7) << 4)));
          // SWAPPED: A = W fragment, B = x fragment -> D[wcol][xrow]
          acc[cf] = __builtin_amdgcn_mfma_f32_16x16x32_f16(bf, af, acc[cf], 0, 0, 0);
        }
      }
      __syncthreads();
      cur ^= 1;
    }
    // after 4 kt-flips: wb[cur] = next head's kt0 (prefetched); wb[cur^1] = DEAD.
    _Float16* dead = &wb[cur ^ 1][0];   // kT: [64 d][88 rows]; vT at +5632 halfs

    // ---- epilogue (register): lane holds cols lg*4+{0..3} of row lr ----
    float sk = 0.f, sk2 = 0.f, sv = 0.f, sv2 = 0.f;
#pragma unroll
    for (int cc = 4; cc < 12; ++cc)
#pragma unroll
      for (int j = 0; j < 4; ++j) {
        float u = acc[cc][j];
        if (cc < 8) { sk += u; sk2 += u * u; } else { sv += u; sv2 += u * u; }
      }
    sk += __shfl_xor(sk, 16, 64);  sk += __shfl_xor(sk, 32, 64);
    sk2 += __shfl_xor(sk2, 16, 64); sk2 += __shfl_xor(sk2, 32, 64);
    sv += __shfl_xor(sv, 16, 64);  sv += __shfl_xor(sv, 32, 64);
    sv2 += __shfl_xor(sv2, 16, 64); sv2 += __shfl_xor(sv2, 32, 64);
    float mk = sk * 0.015625f, mv = sv * 0.015625f;
    float ik = rsqrtf(sk2 * 0.015625f - mk * mk + 1e-5f);
    float iv = rsqrtf(sv2 * 0.015625f - mv * mv + 1e-5f);

    half4 oq[4], ok[4], ov[4];
#pragma unroll
    for (int j = 0; j < 4; ++j) {
      float q0 = acc[0][j], q1 = acc[1][j], q2 = acc[2][j], q3 = acc[3][j];
      oq[0][j] = (_Float16)(q0 * cxj[j] - q1 * sxj[j]);
      oq[1][j] = (_Float16)(q1 * cxj[j] + q0 * sxj[j]);
      oq[2][j] = (_Float16)(q2 * cyj[j] - q3 * syj[j]);
      oq[3][j] = (_Float16)(q3 * cyj[j] + q2 * syj[j]);
      float k0 = (acc[4][j] - mk) * ik, k1 = (acc[5][j] - mk) * ik;
      float k2 = (acc[6][j] - mk) * ik, k3 = (acc[7][j] - mk) * ik;
      ok[0][j] = (_Float16)(k0 * cxj[j] - k1 * sxj[j]);
      ok[1][j] = (_Float16)(k1 * cxj[j] + k0 * sxj[j]);
      ok[2][j] = (_Float16)(k2 * cyj[j] - k3 * syj[j]);
      ok[3][j] = (_Float16)(k3 * cyj[j] + k2 * syj[j]);
      ov[0][j] = (_Float16)((acc[8][j]  - mv) * iv);
      ov[1][j] = (_Float16)((acc[9][j]  - mv) * iv);
      ov[2][j] = (_Float16)((acc[10][j] - mv) * iv);
      ov[3][j] = (_Float16)((acc[11][j] - mv) * iv);
    }
    // q -> global
    size_t qbase = (size_t)myrow * 512 + h * 64 + lg * 4;
#pragma unroll
    for (int cc = 0; cc < 4; ++cc) *(half4*)(q16 + qbase + cc * 16) = oq[cc];
    // k,v -> dead buffer, transposed: kT[d][row], vT[e][row] (stride 88)
#pragma unroll
    for (int cc = 0; cc < 4; ++cc)
#pragma unroll
      for (int j = 0; j < 4; ++j) {
        int dr = (cc * 16 + lg * 4 + j) * 88 + wv * 16 + lr;
        dead[dr] = ok[cc][j];
        dead[5632 + dr] = ov[cc][j];
      }
    __syncthreads();

    // ---- dots partial: D[e][d] = sum_rows kT[d][row] vT[e][row], K=64 ----
    f32x4 dacc[4] = {};
#pragma unroll
    for (int ks = 0; ks < 2; ++ks) {
      half8 adf = *(const half8*)(dead + (wv * 16 + lr) * 88 + ks * 32 + lg * 8);
#pragma unroll
      for (int ep = 0; ep < 4; ++ep) {
        half8 bdf = *(const half8*)(dead + 5632 + (ep * 16 + lr) * 88 + ks * 32 + lg * 8);
        dacc[ep] = __builtin_amdgcn_mfma_f32_16x16x32_f16(adf, bdf, dacc[ep], 0, 0, 0);
      }
    }
    __syncthreads();   // protect dead buffer from next head's prefetch
    // partial layout [e][d]: lane holds d = wv*16 + lg*4+{0..3}, e = ep*16+lr
    _Float16* pdst = part16 + ((size_t)blockIdx.x * 8 + h) * 4096;
#pragma unroll
    for (int ep = 0; ep < 4; ++ep) {
      half4 o;
#pragma unroll
      for (int j = 0; j < 4; ++j) o[j] = (_Float16)dacc[ep][j];
      *(half4*)(pdst + (ep * 16 + lr) * 64 + wv * 16 + lg * 4) = o;
    }
  }
}

// ---------------- K2: reduce 512 rowtile partials -> dots fp32 [32 bh][e*64+d] ----
// grid(256): bh = blockIdx>>3, slice = blockIdx&7 (512 halfs). half8 loads,
// wave w covers rowtiles w*32..+31, cross-wave LDS reduce.
__global__ void __launch_bounds__(256) k_pred(const _Float16* __restrict__ part16,
                                              float* __restrict__ dots) {
  __shared__ float red[4][512];
  const int bh = blockIdx.x >> 3, sl = blockIdx.x & 7;
  const int b = bh >> 3, h = bh & 7;
  const int t = threadIdx.x, wv = t >> 6, l = t & 63;
  float s[8] = {};
  const _Float16* base = part16 + ((size_t)(b * 128) * 8 + h) * 4096 + sl * 512 + l * 8;
#pragma unroll 4
  for (int i = 0; i < 32; ++i) {
    int rt = wv * 32 + i;
    half8 v = *(const half8*)(base + (size_t)rt * 32768);
#pragma unroll
    for (int m = 0; m < 8; ++m) s[m] += (float)v[m];
  }
#pragma unroll
  for (int m = 0; m < 8; ++m) red[wv][l * 8 + m] = s[m];
  __syncthreads();
#pragma unroll
  for (int e = t; e < 512; e += 256) {
    float r = red[0][e] + red[1][e] + red[2][e] + red[3][e];
    dots[(size_t)bh * 4096 + sl * 512 + e] = r;
  }
}

// ---------------- K2b: wdt[b][j][h*64+d] = (1/N) sum_e dotsT[e][d] wout[h*64+e][j]
// grid(32): bid = b*8+h. dots input is [e][d] orientation.
__global__ void __launch_bounds__(256) k_wd(const float* __restrict__ dots,
                                            const float* __restrict__ wout,
                                            _Float16* __restrict__ wdt) {
  __shared__ alignas(16) _Float16 a_lds[4096];    // [64 d][64 e] swizzled, 8 KB
  __shared__ alignas(16) _Float16 b_lds[16384];   // [256 j][64 e] swizzled, 32 KB
  const int bid = blockIdx.x, b = bid >> 3, hh = bid & 7;
  const int t = threadIdx.x, wv = t >> 6, l = t & 63, lr = l & 15, lg = l >> 4;

  // A: dots [e][d] fp32 -> a_lds [d][e] fp16 (scaled)
#pragma unroll
  for (int g = 0; g < 4; ++g) {
    int i4 = (g * 256 + t) * 4;  // 0..4095, e = i4>>6, d = i4&63
    f32x4 s = *(const f32x4*)(dots + (size_t)bid * 4096 + i4);
    int e = i4 >> 6, d0 = i4 & 63;
#pragma unroll
    for (int m = 0; m < 4; ++m) {
      int d = d0 + m;
      *(_Float16*)((char*)a_lds + d * 128 + ((e * 2) ^ ((d & 7) << 4))) =
          (_Float16)(s[m] * (1.0f / 8192.0f));
    }
  }
  // B: wout rows hh*64..+63, transposed to [j][e] fp16
#pragma unroll
  for (int g = 0; g < 16; ++g) {
    int i4 = (g * 256 + t) * 4;  // 0..16383
    int e = i4 >> 8, j0 = i4 & 255;
    f32x4 u = *(const f32x4*)(wout + (size_t)(hh * 64 + e) * 256 + j0);
#pragma unroll
    for (int m = 0; m < 4; ++m) {
      int j = j0 + m;
      *(_Float16*)((char*)b_lds + j * 128 + ((e * 2) ^ ((j & 7) << 4))) = (_Float16)u[m];
    }
  }
  __syncthreads();

  f32x4 acc[4][4] = {};
#pragma unroll
  for (int sp = 0; sp < 2; ++sp) {
    int kb = sp * 64 + lg * 16;
    half8 af[4], bf[4];
#pragma unroll
    for (int ad = 0; ad < 4; ++ad) {
      int d = ad * 16 + lr;
      af[ad] = *(const half8*)((const char*)a_lds + d * 128 + (kb ^ ((d & 7) << 4)));
    }
#pragma unroll
    for (int bj = 0; bj < 4; ++bj) {
      int j = wv * 64 + bj * 16 + lr;
      bf[bj] = *(const half8*)((const char*)b_lds + j * 128 + (kb ^ ((j & 7) << 4)));
    }
#pragma unroll
    for (int ad = 0; ad < 4; ++ad)
#pragma unroll
      for (int bj = 0; bj < 4; ++bj)
        acc[ad][bj] = __builtin_amdgcn_mfma_f32_16x16x32_f16(af[ad], bf[bj], acc[ad][bj], 0, 0, 0);
  }
  // D[row=d][col=j]: lane holds d = ad*16+lg*4+{0..3}, j = wv*64+bj*16+lr
#pragma unroll
  for (int ad = 0; ad < 4; ++ad)
#pragma unroll
    for (int bj = 0; bj < 4; ++bj) {
      int j = wv * 64 + bj * 16 + lr;
      half4 o;
#pragma unroll
      for (int jj = 0; jj < 4; ++jj) o[jj] = (_Float16)acc[ad][bj][jj];
      *(half4*)(wdt + (size_t)b * 131072 + (size_t)j * 512 + hh * 64 + ad * 16 + lg * 4) = o;
    }
}

// ---------------- K3: out = q16 @ wdt[b] + b_out ----------------
__global__ void __launch_bounds__(256) k_out(const _Float16* __restrict__ q16,
                                             const _Float16* __restrict__ wdt,
                                             const float* __restrict__ bout,
                                             float* __restrict__ out) {
  __shared__ alignas(16) _Float16 qa[2][4096];     // [64 rows][64 K] 8 KB x2
  __shared__ alignas(16) _Float16 wtile[2][16384]; // [256 cols][64 K] 32 KB x2
  const int row0 = blockIdx.x * 64;
  const int b = row0 >> 13;
  const _Float16* wb = wdt + (size_t)b * 131072;
  const int t = threadIdx.x, wv = t >> 6, l = t & 63, lr = l & 15, lg = l >> 4;

  auto stage = [&](int buf, int kt) {
#pragma unroll
    for (int call = 0; call < 2; ++call) {
      int ob = (call * 4 + wv) * 1024;
      int o = ob + l * 16;
      int r = o >> 7;
      int kb = (o & 127) ^ ((r & 7) << 4);
      const char* src = (const char*)(q16 + (size_t)(row0 + r) * 512 + kt * 64) + kb;
      GLL(src, (char*)&qa[buf][0] + ob);
    }
#pragma unroll
    for (int call = 0; call < 8; ++call) {
      int ob = (call * 4 + wv) * 1024;
      int o = ob + l * 16;
      int c = o >> 7;
      int kb = (o & 127) ^ ((c & 7) << 4);
      const char* src = (const char*)(wb + (size_t)c * 512 + kt * 64) + kb;
      GLL(src, (char*)&wtile[buf][0] + ob);
    }
  };

  f32x4 acc[16] = {};
  stage(0, 0);
  __syncthreads();
#pragma unroll 1
  for (int kt = 0; kt < 8; ++kt) {
    int cur = kt & 1;
    if (kt < 7) stage(cur ^ 1, kt + 1);
    const int arow = wv * 16 + lr;
#pragma unroll
    for (int sp = 0; sp < 2; ++sp) {
      int kb = sp * 64 + lg * 16;
      half8 af = *(const half8*)((const char*)&qa[cur][0] + arow * 128 + (kb ^ ((arow & 7) << 4)));
#pragma unroll
      for (int cf = 0; cf < 16; ++cf) {
        int c = cf * 16 + lr;
        half8 bf = *(const half8*)((const char*)&wtile[cur][0] + c * 128 + (kb ^ ((c & 7) << 4)));
        acc[cf] = __builtin_amdgcn_mfma_f32_16x16x32_f16(af, bf, acc[cf], 0, 0, 0);
      }
    }
    __syncthreads();
  }
#pragma unroll
  for (int cf = 0; cf < 16; ++cf) {
    int col = cf * 16 + lr;
    float bo = bout[col];
#pragma unroll
    for (int j = 0; j < 4; ++j) {
      int grow = row0 + wv * 16 + lg * 4 + j;
      out[(size_t)grow * 256 + col] = acc[cf][j] + bo;
    }
  }
}

// ---------------- launch ----------------
extern "C" void kernel_launch(void* const* d_in, const int* in_sizes, int n_in,
                              void* d_out, int out_size, void* d_ws, size_t ws_size,
                              hipStream_t stream) {
  const float* x    = (const float*)d_in[0];
  const float* pos  = (const float*)d_in[1];
  const float* wqkv = (const float*)d_in[2];
  const float* wout = (const float*)d_in[3];
  const float* bout = (const float*)d_in[4];
  float* out = (float*)d_out;
  char* ws = (char*)d_ws;

  _Float16* wt16   = (_Float16*)(ws + 0);          //    786,432 B
  _Float16* q16    = (_Float16*)(ws + 786432);     // 33,554,432 B
  _Float16* part16 = (_Float16*)(ws + 34340864);   // 33,554,432 B
  float*    dots   = (float*)   (ws + 67895296);   //    524,288 B
  _Float16* wdt    = (_Float16*)(ws + 68419584);   //  1,048,576 B (end 69,468,160)

  k_cvt_w<<<1536, 256, 0, stream>>>(wqkv, wt16);
  k_qkv<<<512, 256, 0, stream>>>(x, wt16, pos, q16, part16);
  k_pred<<<256, 256, 0, stream>>>(part16, dots);
  k_wd<<<32, 256, 0, stream>>>(dots, wout, wdt);
  k_out<<<512, 256, 0, stream>>>(q16, wdt, bout, out);
}

// Round 6
// 106.875 us; speedup vs baseline: 1.0605x; 1.0605x over previous
//
#include <hip/hip_runtime.h>
#include <hip/hip_fp16.h>

#define BB 4
#define NN 8192
#define DD 256
#define HH 8
#define MM 32768   // BB*NN

typedef __attribute__((ext_vector_type(8))) _Float16 half8;
typedef __attribute__((ext_vector_type(4))) _Float16 half4;
typedef __attribute__((ext_vector_type(4))) float f32x4;

#define GLL(src, dst)                                                        \
  __builtin_amdgcn_global_load_lds(                                          \
      (const __attribute__((address_space(1))) void*)(src),                  \
      (__attribute__((address_space(3))) void*)(dst), 16, 0, 0)

// ---------------- K0: W conversion ----------------
// W_qkv [256][1536] fp32 -> Wt [1536][256] fp16 (transposed)
__global__ void __launch_bounds__(256) k_cvt_w(const float* __restrict__ w,
                                               _Float16* __restrict__ wt) {
  int idx = blockIdx.x * 256 + threadIdx.x;  // 0..393215
  int k = idx / 1536, c = idx % 1536;
  wt[(size_t)c * 256 + k] = (_Float16)w[idx];
}

// ---------------- K1: qkv GEMM + norm + rotary + fused dots-partial ----------------
// grid(1024): bid -> rowtile = bid>>1 (64 rows), head-pair h0 = (bid&1)*4 (4 heads).
// 4 waves. x-fragments in REGISTERS (kt loop fully unrolled -> static indexing,
// no scratch spill). LDS = W double-buffer only (48 KB -> 3 blocks/CU).
__global__ void __launch_bounds__(256, 3) k_qkv(const float* __restrict__ x,
                                                const _Float16* __restrict__ wt,
                                                const float* __restrict__ pos,
                                                _Float16* __restrict__ q16,
                                                _Float16* __restrict__ part16) {
  __shared__ alignas(16) _Float16 wb[2][12288];   // [192 cols][64 K] swizzled, 24 KB x2
  const int bid = blockIdx.x;
  const int rowtile = bid >> 1;
  const int row0 = rowtile * 64;
  const int h0 = (bid & 1) * 4;
  const int t = threadIdx.x;
  const int wv = t >> 6, l = t & 63, lr = l & 15, lg = l >> 4;
  const int myrow = row0 + wv * 16 + lr;

  // ---- x fragments: direct coalesced global loads, fp32 -> fp16, in regs ----
  half8 afr[8];
#pragma unroll
  for (int c = 0; c < 8; ++c) {      // c = kt*2 + sp
    const float* src = x + (size_t)myrow * 256 + c * 32 + lg * 8;
    float4 a = *(const float4*)src;
    float4 b = *(const float4*)(src + 4);
    half8 hv;
    hv[0] = (_Float16)a.x; hv[1] = (_Float16)a.y; hv[2] = (_Float16)a.z; hv[3] = (_Float16)a.w;
    hv[4] = (_Float16)b.x; hv[5] = (_Float16)b.y; hv[6] = (_Float16)b.z; hv[7] = (_Float16)b.w;
    afr[c] = hv;
  }

  // ---- hoist rotary angles: freq index = lg*4+j ----
  const float px = pos[(size_t)myrow * 2 + 0] * 64.0f;
  const float py = pos[(size_t)myrow * 2 + 1] * 64.0f;
  float sxj[4], cxj[4], syj[4], cyj[4];
#pragma unroll
  for (int j = 0; j < 4; ++j) {
    float invf = exp2f((float)(lg * 4 + j) * -0.8304820237218405f);  // 10000^(-fi/16)
    __sincosf(px * invf, &sxj[j], &cxj[j]);
    __sincosf(py * invf, &syj[j], &cyj[j]);
  }

  // ---- W staging: global_load_lds, pre-swizzled source (hh = absolute head) ----
  auto stageW = [&](int buf, int hh, int kt) {
#pragma unroll
    for (int call = 0; call < 6; ++call) {
      int ob = (call * 4 + wv) * 1024;             // wave-uniform dest base (bytes)
      int o = ob + l * 16;                         // this lane's dest byte
      int c = o >> 7;                              // col 0..191
      int kb = (o & 127) ^ ((c & 7) << 4);         // logical K byte
      int gc = ((c >> 6) << 9) + (hh << 6) + (c & 63);  // global wt row
      const char* src = (const char*)(wt + (size_t)gc * 256 + kt * 64) + kb;
      GLL(src, (char*)&wb[buf][0] + ob);
    }
  };

  stageW(0, h0, 0);
  __syncthreads();

  int cur = 0;
#pragma unroll 1
  for (int hh = 0; hh < 4; ++hh) {
    const int h = h0 + hh;
    f32x4 acc[12] = {};
#pragma unroll
    for (int kt = 0; kt < 4; ++kt) {             // FULLY UNROLLED: afr static index
      int ni = (hh << 2) + kt + 1;
      if (ni < 16) stageW(cur ^ 1, h0 + (ni >> 2), ni & 3);
      const char* wbp = (const char*)&wb[cur][0];
#pragma unroll
      for (int sp = 0; sp < 2; ++sp) {
        half8 af = afr[kt * 2 + sp];
        int wkb = sp * 64 + lg * 16;
#pragma unroll
        for (int cf = 0; cf < 12; ++cf) {
          int c = cf * 16 + lr;
          half8 bf = *(const half8*)(wbp + c * 128 + (wkb ^ ((c & 7) << 4)));
          // SWAPPED: A = W fragment, B = x fragment -> D[wcol][xrow]
          acc[cf] = __builtin_amdgcn_mfma_f32_16x16x32_f16(bf, af, acc[cf], 0, 0, 0);
        }
      }
      __syncthreads();
      cur ^= 1;
    }
    // after 4 kt-flips: wb[cur] = next head's kt0 (prefetched); wb[cur^1] = DEAD.
    _Float16* dead = &wb[cur ^ 1][0];   // kT: [64 d][88 rows]; vT at +5632 halfs

    // ---- epilogue (register): lane holds cols lg*4+{0..3} of row lr ----
    float sk = 0.f, sk2 = 0.f, sv = 0.f, sv2 = 0.f;
#pragma unroll
    for (int cc = 4; cc < 12; ++cc)
#pragma unroll
      for (int j = 0; j < 4; ++j) {
        float u = acc[cc][j];
        if (cc < 8) { sk += u; sk2 += u * u; } else { sv += u; sv2 += u * u; }
      }
    sk += __shfl_xor(sk, 16, 64);  sk += __shfl_xor(sk, 32, 64);
    sk2 += __shfl_xor(sk2, 16, 64); sk2 += __shfl_xor(sk2, 32, 64);
    sv += __shfl_xor(sv, 16, 64);  sv += __shfl_xor(sv, 32, 64);
    sv2 += __shfl_xor(sv2, 16, 64); sv2 += __shfl_xor(sv2, 32, 64);
    float mk = sk * 0.015625f, mv = sv * 0.015625f;
    float ik = rsqrtf(sk2 * 0.015625f - mk * mk + 1e-5f);
    float iv = rsqrtf(sv2 * 0.015625f - mv * mv + 1e-5f);

    half4 oq[4], ok[4], ov[4];
#pragma unroll
    for (int j = 0; j < 4; ++j) {
      float q0 = acc[0][j], q1 = acc[1][j], q2 = acc[2][j], q3 = acc[3][j];
      oq[0][j] = (_Float16)(q0 * cxj[j] - q1 * sxj[j]);
      oq[1][j] = (_Float16)(q1 * cxj[j] + q0 * sxj[j]);
      oq[2][j] = (_Float16)(q2 * cyj[j] - q3 * syj[j]);
      oq[3][j] = (_Float16)(q3 * cyj[j] + q2 * syj[j]);
      float k0 = (acc[4][j] - mk) * ik, k1 = (acc[5][j] - mk) * ik;
      float k2 = (acc[6][j] - mk) * ik, k3 = (acc[7][j] - mk) * ik;
      ok[0][j] = (_Float16)(k0 * cxj[j] - k1 * sxj[j]);
      ok[1][j] = (_Float16)(k1 * cxj[j] + k0 * sxj[j]);
      ok[2][j] = (_Float16)(k2 * cyj[j] - k3 * syj[j]);
      ok[3][j] = (_Float16)(k3 * cyj[j] + k2 * syj[j]);
      ov[0][j] = (_Float16)((acc[8][j]  - mv) * iv);
      ov[1][j] = (_Float16)((acc[9][j]  - mv) * iv);
      ov[2][j] = (_Float16)((acc[10][j] - mv) * iv);
      ov[3][j] = (_Float16)((acc[11][j] - mv) * iv);
    }
    // q -> global
    size_t qbase = (size_t)myrow * 512 + h * 64 + lg * 4;
#pragma unroll
    for (int cc = 0; cc < 4; ++cc) *(half4*)(q16 + qbase + cc * 16) = oq[cc];
    // k,v -> dead buffer, transposed: kT[d][row], vT[e][row] (stride 88)
#pragma unroll
    for (int cc = 0; cc < 4; ++cc)
#pragma unroll
      for (int j = 0; j < 4; ++j) {
        int dr = (cc * 16 + lg * 4 + j) * 88 + wv * 16 + lr;
        dead[dr] = ok[cc][j];
        dead[5632 + dr] = ov[cc][j];
      }
    __syncthreads();

    // ---- dots partial: D[e][d] = sum_rows kT[d][row] vT[e][row], K=64 ----
    f32x4 dacc[4] = {};
#pragma unroll
    for (int ks = 0; ks < 2; ++ks) {
      half8 adf = *(const half8*)(dead + (wv * 16 + lr) * 88 + ks * 32 + lg * 8);
#pragma unroll
      for (int ep = 0; ep < 4; ++ep) {
        half8 bdf = *(const half8*)(dead + 5632 + (ep * 16 + lr) * 88 + ks * 32 + lg * 8);
        dacc[ep] = __builtin_amdgcn_mfma_f32_16x16x32_f16(adf, bdf, dacc[ep], 0, 0, 0);
      }
    }
    __syncthreads();   // protect dead buffer from next head's prefetch
    // partial layout [e][d]: lane holds d = wv*16 + lg*4+{0..3}, e = ep*16+lr
    _Float16* pdst = part16 + ((size_t)rowtile * 8 + h) * 4096;
#pragma unroll
    for (int ep = 0; ep < 4; ++ep) {
      half4 o;
#pragma unroll
      for (int j = 0; j < 4; ++j) o[j] = (_Float16)dacc[ep][j];
      *(half4*)(pdst + (ep * 16 + lr) * 64 + wv * 16 + lg * 4) = o;
    }
  }
}

// ---------------- K2: reduce 512 rowtile partials -> dots fp32 [32 bh][e*64+d] ----
// grid(256): bh = blockIdx>>3, slice = blockIdx&7 (512 halfs). half8 loads,
// wave w covers rowtiles w*32..+31, cross-wave LDS reduce.
__global__ void __launch_bounds__(256) k_pred(const _Float16* __restrict__ part16,
                                              float* __restrict__ dots) {
  __shared__ float red[4][512];
  const int bh = blockIdx.x >> 3, sl = blockIdx.x & 7;
  const int b = bh >> 3, h = bh & 7;
  const int t = threadIdx.x, wv = t >> 6, l = t & 63;
  float s[8] = {};
  const _Float16* base = part16 + ((size_t)(b * 128) * 8 + h) * 4096 + sl * 512 + l * 8;
#pragma unroll 4
  for (int i = 0; i < 32; ++i) {
    int rt = wv * 32 + i;
    half8 v = *(const half8*)(base + (size_t)rt * 32768);
#pragma unroll
    for (int m = 0; m < 8; ++m) s[m] += (float)v[m];
  }
#pragma unroll
  for (int m = 0; m < 8; ++m) red[wv][l * 8 + m] = s[m];
  __syncthreads();
#pragma unroll
  for (int e = t; e < 512; e += 256) {
    float r = red[0][e] + red[1][e] + red[2][e] + red[3][e];
    dots[(size_t)bh * 4096 + sl * 512 + e] = r;
  }
}

// ---------------- K2b: wdt[b][j][h*64+d] = (1/N) sum_e dotsT[e][d] wout[h*64+e][j]
// grid(32): bid = b*8+h. dots input is [e][d] orientation.
__global__ void __launch_bounds__(256) k_wd(const float* __restrict__ dots,
                                            const float* __restrict__ wout,
                                            _Float16* __restrict__ wdt) {
  __shared__ alignas(16) _Float16 a_lds[4096];    // [64 d][64 e] swizzled, 8 KB
  __shared__ alignas(16) _Float16 b_lds[16384];   // [256 j][64 e] swizzled, 32 KB
  const int bid = blockIdx.x, b = bid >> 3, hh = bid & 7;
  const int t = threadIdx.x, wv = t >> 6, l = t & 63, lr = l & 15, lg = l >> 4;

  // A: dots [e][d] fp32 -> a_lds [d][e] fp16 (scaled)
#pragma unroll
  for (int g = 0; g < 4; ++g) {
    int i4 = (g * 256 + t) * 4;  // 0..4095, e = i4>>6, d = i4&63
    f32x4 s = *(const f32x4*)(dots + (size_t)bid * 4096 + i4);
    int e = i4 >> 6, d0 = i4 & 63;
#pragma unroll
    for (int m = 0; m < 4; ++m) {
      int d = d0 + m;
      *(_Float16*)((char*)a_lds + d * 128 + ((e * 2) ^ ((d & 7) << 4))) =
          (_Float16)(s[m] * (1.0f / 8192.0f));
    }
  }
  // B: wout rows hh*64..+63, transposed to [j][e] fp16
#pragma unroll
  for (int g = 0; g < 16; ++g) {
    int i4 = (g * 256 + t) * 4;  // 0..16383
    int e = i4 >> 8, j0 = i4 & 255;
    f32x4 u = *(const f32x4*)(wout + (size_t)(hh * 64 + e) * 256 + j0);
#pragma unroll
    for (int m = 0; m < 4; ++m) {
      int j = j0 + m;
      *(_Float16*)((char*)b_lds + j * 128 + ((e * 2) ^ ((j & 7) << 4))) = (_Float16)u[m];
    }
  }
  __syncthreads();

  f32x4 acc[4][4] = {};
#pragma unroll
  for (int sp = 0; sp < 2; ++sp) {
    int kb = sp * 64 + lg * 16;
    half8 af[4], bf[4];
#pragma unroll
    for (int ad = 0; ad < 4; ++ad) {
      int d = ad * 16 + lr;
      af[ad] = *(const half8*)((const char*)a_lds + d * 128 + (kb ^ ((d & 7) << 4)));
    }
#pragma unroll
    for (int bj = 0; bj < 4; ++bj) {
      int j = wv * 64 + bj * 16 + lr;
      bf[bj] = *(const half8*)((const char*)b_lds + j * 128 + (kb ^ ((j & 7) << 4)));
    }
#pragma unroll
    for (int ad = 0; ad < 4; ++ad)
#pragma unroll
      for (int bj = 0; bj < 4; ++bj)
        acc[ad][bj] = __builtin_amdgcn_mfma_f32_16x16x32_f16(af[ad], bf[bj], acc[ad][bj], 0, 0, 0);
  }
  // D[row=d][col=j]: lane holds d = ad*16+lg*4+{0..3}, j = wv*64+bj*16+lr
#pragma unroll
  for (int ad = 0; ad < 4; ++ad)
#pragma unroll
    for (int bj = 0; bj < 4; ++bj) {
      int j = wv * 64 + bj * 16 + lr;
      half4 o;
#pragma unroll
      for (int jj = 0; jj < 4; ++jj) o[jj] = (_Float16)acc[ad][bj][jj];
      *(half4*)(wdt + (size_t)b * 131072 + (size_t)j * 512 + hh * 64 + ad * 16 + lg * 4) = o;
    }
}

// ---------------- K3: out = q16 @ wdt[b] + b_out ----------------
__global__ void __launch_bounds__(256) k_out(const _Float16* __restrict__ q16,
                                             const _Float16* __restrict__ wdt,
                                             const float* __restrict__ bout,
                                             float* __restrict__ out) {
  __shared__ alignas(16) _Float16 qa[2][4096];     // [64 rows][64 K] 8 KB x2
  __shared__ alignas(16) _Float16 wtile[2][16384]; // [256 cols][64 K] 32 KB x2
  const int row0 = blockIdx.x * 64;
  const int b = row0 >> 13;
  const _Float16* wb = wdt + (size_t)b * 131072;
  const int t = threadIdx.x, wv = t >> 6, l = t & 63, lr = l & 15, lg = l >> 4;

  auto stage = [&](int buf, int kt) {
#pragma unroll
    for (int call = 0; call < 2; ++call) {
      int ob = (call * 4 + wv) * 1024;
      int o = ob + l * 16;
      int r = o >> 7;
      int kb = (o & 127) ^ ((r & 7) << 4);
      const char* src = (const char*)(q16 + (size_t)(row0 + r) * 512 + kt * 64) + kb;
      GLL(src, (char*)&qa[buf][0] + ob);
    }
#pragma unroll
    for (int call = 0; call < 8; ++call) {
      int ob = (call * 4 + wv) * 1024;
      int o = ob + l * 16;
      int c = o >> 7;
      int kb = (o & 127) ^ ((c & 7) << 4);
      const char* src = (const char*)(wb + (size_t)c * 512 + kt * 64) + kb;
      GLL(src, (char*)&wtile[buf][0] + ob);
    }
  };

  f32x4 acc[16] = {};
  stage(0, 0);
  __syncthreads();
#pragma unroll 1
  for (int kt = 0; kt < 8; ++kt) {
    int cur = kt & 1;
    if (kt < 7) stage(cur ^ 1, kt + 1);
    const int arow = wv * 16 + lr;
#pragma unroll
    for (int sp = 0; sp < 2; ++sp) {
      int kb = sp * 64 + lg * 16;
      half8 af = *(const half8*)((const char*)&qa[cur][0] + arow * 128 + (kb ^ ((arow & 7) << 4)));
#pragma unroll
      for (int cf = 0; cf < 16; ++cf) {
        int c = cf * 16 + lr;
        half8 bf = *(const half8*)((const char*)&wtile[cur][0] + c * 128 + (kb ^ ((c & 7) << 4)));
        acc[cf] = __builtin_amdgcn_mfma_f32_16x16x32_f16(af, bf, acc[cf], 0, 0, 0);
      }
    }
    __syncthreads();
  }
#pragma unroll
  for (int cf = 0; cf < 16; ++cf) {
    int col = cf * 16 + lr;
    float bo = bout[col];
#pragma unroll
    for (int j = 0; j < 4; ++j) {
      int grow = row0 + wv * 16 + lg * 4 + j;
      out[(size_t)grow * 256 + col] = acc[cf][j] + bo;
    }
  }
}

// ---------------- launch ----------------
extern "C" void kernel_launch(void* const* d_in, const int* in_sizes, int n_in,
                              void* d_out, int out_size, void* d_ws, size_t ws_size,
                              hipStream_t stream) {
  const float* x    = (const float*)d_in[0];
  const float* pos  = (const float*)d_in[1];
  const float* wqkv = (const float*)d_in[2];
  const float* wout = (const float*)d_in[3];
  const float* bout = (const float*)d_in[4];
  float* out = (float*)d_out;
  char* ws = (char*)d_ws;

  _Float16* wt16   = (_Float16*)(ws + 0);          //    786,432 B
  _Float16* q16    = (_Float16*)(ws + 786432);     // 33,554,432 B
  _Float16* part16 = (_Float16*)(ws + 34340864);   // 33,554,432 B
  float*    dots   = (float*)   (ws + 67895296);   //    524,288 B
  _Float16* wdt    = (_Float16*)(ws + 68419584);   //  1,048,576 B (end 69,468,160)

  k_cvt_w<<<1536, 256, 0, stream>>>(wqkv, wt16);
  k_qkv<<<1024, 256, 0, stream>>>(x, wt16, pos, q16, part16);
  k_pred<<<256, 256, 0, stream>>>(part16, dots);
  k_wd<<<32, 256, 0, stream>>>(dots, wout, wdt);
  k_out<<<512, 256, 0, stream>>>(q16, wdt, bout, out);
}

// Round 7
// 102.273 us; speedup vs baseline: 1.1082x; 1.0450x over previous
//
#include <hip/hip_runtime.h>
#include <hip/hip_fp16.h>

#define BB 4
#define NN 8192
#define DD 256
#define HH 8
#define MM 32768   // BB*NN

typedef __attribute__((ext_vector_type(8))) _Float16 half8;
typedef __attribute__((ext_vector_type(4))) _Float16 half4;
typedef __attribute__((ext_vector_type(4))) float f32x4;

#define GLL(src, dst)                                                        \
  __builtin_amdgcn_global_load_lds(                                          \
      (const __attribute__((address_space(1))) void*)(src),                  \
      (__attribute__((address_space(3))) void*)(dst), 16, 0, 0)

// ---------------- K0: W conversion ----------------
// W_qkv [256][1536] fp32 -> Wt [1536][256] fp16 (transposed)
__global__ void __launch_bounds__(256) k_cvt_w(const float* __restrict__ w,
                                               _Float16* __restrict__ wt) {
  int idx = blockIdx.x * 256 + threadIdx.x;  // 0..393215
  int k = idx / 1536, c = idx % 1536;
  wt[(size_t)c * 256 + k] = (_Float16)w[idx];
}

// ---------------- K1: qkv GEMM + norm + rotary + fused dots-partial ----------------
// grid(512): 64 rows, ALL 8 heads, K=256 in 4 panels of 64. 4 waves.
// x-frags in registers. W staged through a 3-buffer ring (24 KB each) with
// counted vmcnt(6) + raw barrier (T4): stages span phases, no drain-to-0.
// Dots scratch = the just-read (dead) ring buffer at each head boundary.
__global__ void __launch_bounds__(256) k_qkv(const float* __restrict__ x,
                                             const _Float16* __restrict__ wt,
                                             const float* __restrict__ pos,
                                             _Float16* __restrict__ q16,
                                             _Float16* __restrict__ part16) {
  __shared__ alignas(16) _Float16 rbuf[3][12288];  // 3 x [192 cols][64 K] swizzled, 72 KB
  const int row0 = blockIdx.x * 64;
  const int t = threadIdx.x;
  const int wv = t >> 6, l = t & 63, lr = l & 15, lg = l >> 4;
  const int myrow = row0 + wv * 16 + lr;

  // ---- x fragments: coalesced global loads, fp32 -> fp16, registers ----
  half8 afr[8];
#pragma unroll
  for (int c = 0; c < 8; ++c) {      // c = kt*2 + sp
    const float* src = x + (size_t)myrow * 256 + c * 32 + lg * 8;
    float4 a = *(const float4*)src;
    float4 b = *(const float4*)(src + 4);
    half8 hv;
    hv[0] = (_Float16)a.x; hv[1] = (_Float16)a.y; hv[2] = (_Float16)a.z; hv[3] = (_Float16)a.w;
    hv[4] = (_Float16)b.x; hv[5] = (_Float16)b.y; hv[6] = (_Float16)b.z; hv[7] = (_Float16)b.w;
    afr[c] = hv;
  }

  // ---- rotary angles: freq index = lg*4+j ----
  const float px = pos[(size_t)myrow * 2 + 0] * 64.0f;
  const float py = pos[(size_t)myrow * 2 + 1] * 64.0f;
  float sxj[4], cxj[4], syj[4], cyj[4];
#pragma unroll
  for (int j = 0; j < 4; ++j) {
    float invf = exp2f((float)(lg * 4 + j) * -0.8304820237218405f);  // 10000^(-fi/16)
    __sincosf(px * invf, &sxj[j], &cxj[j]);
    __sincosf(py * invf, &syj[j], &cyj[j]);
  }

  // ---- W stage for phase p (p = h*4 + kt); data index wraps past 31 ----
  auto stageP = [&](int p) {
    const int pd = p & 31;
    const int hh = pd >> 2, kt = pd & 3;
    char* dst = (char*)&rbuf[p % 3][0];
#pragma unroll
    for (int call = 0; call < 6; ++call) {
      int ob = (call * 4 + wv) * 1024;             // wave-uniform dest base (bytes)
      int o = ob + l * 16;                         // this lane's dest byte
      int c = o >> 7;                              // col 0..191
      int kb = (o & 127) ^ ((c & 7) << 4);         // logical K byte (XOR swizzle)
      int gc = ((c >> 6) << 9) + (hh << 6) + (c & 63);  // global wt row
      const char* src = (const char*)(wt + (size_t)gc * 256 + kt * 64) + kb;
      GLL(src, dst + ob);
    }
  };

  stageP(0); stageP(1);
  asm volatile("s_waitcnt vmcnt(6)" ::: "memory");   // stage(0) complete
  __builtin_amdgcn_s_barrier();

#pragma unroll 1
  for (int h = 0; h < 8; ++h) {
    f32x4 acc[12] = {};
#pragma unroll
    for (int kt = 0; kt < 4; ++kt) {               // unrolled: afr static index
      const int p = h * 4 + kt;
      stageP(p + 2);                               // 6 GLL, lands 2 phases ahead
      const char* wbp = (const char*)&rbuf[p % 3][0];
#pragma unroll
      for (int sp = 0; sp < 2; ++sp) {
        half8 af = afr[kt * 2 + sp];
        int wkb = sp * 64 + lg * 16;
#pragma unroll
        for (int cf = 0; cf < 12; ++cf) {
          int c = cf * 16 + lr;
          half8 bf = *(const half8*)(wbp + c * 128 + (wkb ^ ((c & 7) << 4)));
          // SWAPPED: A = W fragment, B = x fragment -> D[wcol][xrow]
          acc[cf] = __builtin_amdgcn_mfma_f32_16x16x32_f16(bf, af, acc[cf], 0, 0, 0);
        }
      }
      // counted: leave the newest stage (6 GLL) in flight; ensure p+1's arrived
      asm volatile("s_waitcnt vmcnt(6)" ::: "memory");
      __builtin_amdgcn_s_barrier();
    }
    // rbuf[(4h+3)%3] == rbuf[h%3] is now dead until stage(4h+6) (issued after dots)
    _Float16* dead = &rbuf[h % 3][0];   // kT: [64 d][88 rows]; vT at +5632 halfs

    // ---- epilogue (register): lane holds cols lg*4+{0..3} of row lr ----
    float sk = 0.f, sk2 = 0.f, sv = 0.f, sv2 = 0.f;
#pragma unroll
    for (int cc = 4; cc < 12; ++cc)
#pragma unroll
      for (int j = 0; j < 4; ++j) {
        float u = acc[cc][j];
        if (cc < 8) { sk += u; sk2 += u * u; } else { sv += u; sv2 += u * u; }
      }
    sk += __shfl_xor(sk, 16, 64);  sk += __shfl_xor(sk, 32, 64);
    sk2 += __shfl_xor(sk2, 16, 64); sk2 += __shfl_xor(sk2, 32, 64);
    sv += __shfl_xor(sv, 16, 64);  sv += __shfl_xor(sv, 32, 64);
    sv2 += __shfl_xor(sv2, 16, 64); sv2 += __shfl_xor(sv2, 32, 64);
    float mk = sk * 0.015625f, mv = sv * 0.015625f;
    float ik = rsqrtf(sk2 * 0.015625f - mk * mk + 1e-5f);
    float iv = rsqrtf(sv2 * 0.015625f - mv * mv + 1e-5f);

    half4 oq[4], ok[4], ov[4];
#pragma unroll
    for (int j = 0; j < 4; ++j) {
      float q0 = acc[0][j], q1 = acc[1][j], q2 = acc[2][j], q3 = acc[3][j];
      oq[0][j] = (_Float16)(q0 * cxj[j] - q1 * sxj[j]);
      oq[1][j] = (_Float16)(q1 * cxj[j] + q0 * sxj[j]);
      oq[2][j] = (_Float16)(q2 * cyj[j] - q3 * syj[j]);
      oq[3][j] = (_Float16)(q3 * cyj[j] + q2 * syj[j]);
      float k0 = (acc[4][j] - mk) * ik, k1 = (acc[5][j] - mk) * ik;
      float k2 = (acc[6][j] - mk) * ik, k3 = (acc[7][j] - mk) * ik;
      ok[0][j] = (_Float16)(k0 * cxj[j] - k1 * sxj[j]);
      ok[1][j] = (_Float16)(k1 * cxj[j] + k0 * sxj[j]);
      ok[2][j] = (_Float16)(k2 * cyj[j] - k3 * syj[j]);
      ok[3][j] = (_Float16)(k3 * cyj[j] + k2 * syj[j]);
      ov[0][j] = (_Float16)((acc[8][j]  - mv) * iv);
      ov[1][j] = (_Float16)((acc[9][j]  - mv) * iv);
      ov[2][j] = (_Float16)((acc[10][j] - mv) * iv);
      ov[3][j] = (_Float16)((acc[11][j] - mv) * iv);
    }
    // k,v -> dead buffer, transposed: kT[d][row], vT[e][row] (stride 88)
#pragma unroll
    for (int cc = 0; cc < 4; ++cc)
#pragma unroll
      for (int j = 0; j < 4; ++j) {
        int dr = (cc * 16 + lg * 4 + j) * 88 + wv * 16 + lr;
        dead[dr] = ok[cc][j];
        dead[5632 + dr] = ov[cc][j];
      }
    __syncthreads();   // writes visible; also drains in-flight stages (boundary only)

    // ---- dots partial: D[e][d] = sum_rows kT[d][row] vT[e][row], K=64 ----
    f32x4 dacc[4] = {};
#pragma unroll
    for (int ks = 0; ks < 2; ++ks) {
      half8 adf = *(const half8*)(dead + (wv * 16 + lr) * 88 + ks * 32 + lg * 8);
#pragma unroll
      for (int ep = 0; ep < 4; ++ep) {
        half8 bdf = *(const half8*)(dead + 5632 + (ep * 16 + lr) * 88 + ks * 32 + lg * 8);
        dacc[ep] = __builtin_amdgcn_mfma_f32_16x16x32_f16(adf, bdf, dacc[ep], 0, 0, 0);
      }
    }
    __syncthreads();   // dots reads done before next stage overwrites dead buffer

    // q -> global (after syncs so boundary drains don't wait on these stores)
    size_t qbase = (size_t)myrow * 512 + h * 64 + lg * 4;
#pragma unroll
    for (int cc = 0; cc < 4; ++cc) *(half4*)(q16 + qbase + cc * 16) = oq[cc];
    // partial layout [e][d]: lane holds d = wv*16 + lg*4+{0..3}, e = ep*16+lr
    _Float16* pdst = part16 + ((size_t)blockIdx.x * 8 + h) * 4096;
#pragma unroll
    for (int ep = 0; ep < 4; ++ep) {
      half4 o;
#pragma unroll
      for (int j = 0; j < 4; ++j) o[j] = (_Float16)dacc[ep][j];
      *(half4*)(pdst + (ep * 16 + lr) * 64 + wv * 16 + lg * 4) = o;
    }
  }
}

// ---------------- K2: reduce 512 rowtile partials -> dots fp32 [32 bh][e*64+d] ----
__global__ void __launch_bounds__(256) k_pred(const _Float16* __restrict__ part16,
                                              float* __restrict__ dots) {
  __shared__ float red[4][512];
  const int bh = blockIdx.x >> 3, sl = blockIdx.x & 7;
  const int b = bh >> 3, h = bh & 7;
  const int t = threadIdx.x, wv = t >> 6, l = t & 63;
  float s[8] = {};
  const _Float16* base = part16 + ((size_t)(b * 128) * 8 + h) * 4096 + sl * 512 + l * 8;
#pragma unroll 4
  for (int i = 0; i < 32; ++i) {
    int rt = wv * 32 + i;
    half8 v = *(const half8*)(base + (size_t)rt * 32768);
#pragma unroll
    for (int m = 0; m < 8; ++m) s[m] += (float)v[m];
  }
#pragma unroll
  for (int m = 0; m < 8; ++m) red[wv][l * 8 + m] = s[m];
  __syncthreads();
#pragma unroll
  for (int e = t; e < 512; e += 256) {
    float r = red[0][e] + red[1][e] + red[2][e] + red[3][e];
    dots[(size_t)bh * 4096 + sl * 512 + e] = r;
  }
}

// ---------------- K2b: wdt[b][j][h*64+d] = (1/N) sum_e dotsT[e][d] wout[h*64+e][j]
// grid(32, 4): bid = b*8+h, j-quarter = blockIdx.y*64.
__global__ void __launch_bounds__(256) k_wd(const float* __restrict__ dots,
                                            const float* __restrict__ wout,
                                            _Float16* __restrict__ wdt) {
  __shared__ alignas(16) _Float16 a_lds[4096];    // [64 d][64 e] swizzled, 8 KB
  __shared__ alignas(16) _Float16 b_lds[4096];    // [64 jl][64 e] swizzled, 8 KB
  const int bid = blockIdx.x, b = bid >> 3, hh = bid & 7;
  const int j0 = blockIdx.y * 64;
  const int t = threadIdx.x, wv = t >> 6, l = t & 63, lr = l & 15, lg = l >> 4;

  // A: dots [e][d] fp32 -> a_lds [d][e] fp16 (scaled)
#pragma unroll
  for (int g = 0; g < 4; ++g) {
    int i4 = (g * 256 + t) * 4;  // 0..4095, e = i4>>6, d = i4&63
    f32x4 s = *(const f32x4*)(dots + (size_t)bid * 4096 + i4);
    int e = i4 >> 6, d0 = i4 & 63;
#pragma unroll
    for (int m = 0; m < 4; ++m) {
      int d = d0 + m;
      *(_Float16*)((char*)a_lds + d * 128 + ((e * 2) ^ ((d & 7) << 4))) =
          (_Float16)(s[m] * (1.0f / 8192.0f));
    }
  }
  // B: wout rows hh*64..+63, cols j0..+63, transposed to [jl][e] fp16
#pragma unroll
  for (int g = 0; g < 4; ++g) {
    int i4 = (g * 256 + t) * 4;  // 0..4095: e = i4>>6, jl = i4&63
    int e = i4 >> 6, jl0 = i4 & 63;
    f32x4 u = *(const f32x4*)(wout + (size_t)(hh * 64 + e) * 256 + j0 + jl0);
#pragma unroll
    for (int m = 0; m < 4; ++m) {
      int jl = jl0 + m;
      *(_Float16*)((char*)b_lds + jl * 128 + ((e * 2) ^ ((jl & 7) << 4))) = (_Float16)u[m];
    }
  }
  __syncthreads();

  f32x4 acc[4] = {};
#pragma unroll
  for (int sp = 0; sp < 2; ++sp) {
    int kb = sp * 64 + lg * 16;
    half8 bf;
    {
      int jl = wv * 16 + lr;
      bf = *(const half8*)((const char*)b_lds + jl * 128 + (kb ^ ((jl & 7) << 4)));
    }
#pragma unroll
    for (int ad = 0; ad < 4; ++ad) {
      int d = ad * 16 + lr;
      half8 af = *(const half8*)((const char*)a_lds + d * 128 + (kb ^ ((d & 7) << 4)));
      acc[ad] = __builtin_amdgcn_mfma_f32_16x16x32_f16(af, bf, acc[ad], 0, 0, 0);
    }
  }
  // D[row=d][col=j]: lane holds d = ad*16+lg*4+{0..3}, j = j0 + wv*16 + lr
#pragma unroll
  for (int ad = 0; ad < 4; ++ad) {
    int j = j0 + wv * 16 + lr;
    half4 o;
#pragma unroll
    for (int jj = 0; jj < 4; ++jj) o[jj] = (_Float16)acc[ad][jj];
    *(half4*)(wdt + (size_t)b * 131072 + (size_t)j * 512 + hh * 64 + ad * 16 + lg * 4) = o;
  }
}

// ---------------- K3: out = q16 @ wdt[b] + b_out ----------------
__global__ void __launch_bounds__(256) k_out(const _Float16* __restrict__ q16,
                                             const _Float16* __restrict__ wdt,
                                             const float* __restrict__ bout,
                                             float* __restrict__ out) {
  __shared__ alignas(16) _Float16 qa[2][4096];     // [64 rows][64 K] 8 KB x2
  __shared__ alignas(16) _Float16 wtile[2][16384]; // [256 cols][64 K] 32 KB x2
  const int row0 = blockIdx.x * 64;
  const int b = row0 >> 13;
  const _Float16* wb = wdt + (size_t)b * 131072;
  const int t = threadIdx.x, wv = t >> 6, l = t & 63, lr = l & 15, lg = l >> 4;

  auto stage = [&](int buf, int kt) {
#pragma unroll
    for (int call = 0; call < 2; ++call) {
      int ob = (call * 4 + wv) * 1024;
      int o = ob + l * 16;
      int r = o >> 7;
      int kb = (o & 127) ^ ((r & 7) << 4);
      const char* src = (const char*)(q16 + (size_t)(row0 + r) * 512 + kt * 64) + kb;
      GLL(src, (char*)&qa[buf][0] + ob);
    }
#pragma unroll
    for (int call = 0; call < 8; ++call) {
      int ob = (call * 4 + wv) * 1024;
      int o = ob + l * 16;
      int c = o >> 7;
      int kb = (o & 127) ^ ((c & 7) << 4);
      const char* src = (const char*)(wb + (size_t)c * 512 + kt * 64) + kb;
      GLL(src, (char*)&wtile[buf][0] + ob);
    }
  };

  f32x4 acc[16] = {};
  stage(0, 0);
  __syncthreads();
#pragma unroll 1
  for (int kt = 0; kt < 8; ++kt) {
    int cur = kt & 1;
    if (kt < 7) stage(cur ^ 1, kt + 1);
    const int arow = wv * 16 + lr;
#pragma unroll
    for (int sp = 0; sp < 2; ++sp) {
      int kb = sp * 64 + lg * 16;
      half8 af = *(const half8*)((const char*)&qa[cur][0] + arow * 128 + (kb ^ ((arow & 7) << 4)));
#pragma unroll
      for (int cf = 0; cf < 16; ++cf) {
        int c = cf * 16 + lr;
        half8 bf = *(const half8*)((const char*)&wtile[cur][0] + c * 128 + (kb ^ ((c & 7) << 4)));
        acc[cf] = __builtin_amdgcn_mfma_f32_16x16x32_f16(af, bf, acc[cf], 0, 0, 0);
      }
    }
    __syncthreads();
  }
#pragma unroll
  for (int cf = 0; cf < 16; ++cf) {
    int col = cf * 16 + lr;
    float bo = bout[col];
#pragma unroll
    for (int j = 0; j < 4; ++j) {
      int grow = row0 + wv * 16 + lg * 4 + j;
      out[(size_t)grow * 256 + col] = acc[cf][j] + bo;
    }
  }
}

// ---------------- launch ----------------
extern "C" void kernel_launch(void* const* d_in, const int* in_sizes, int n_in,
                              void* d_out, int out_size, void* d_ws, size_t ws_size,
                              hipStream_t stream) {
  const float* x    = (const float*)d_in[0];
  const float* pos  = (const float*)d_in[1];
  const float* wqkv = (const float*)d_in[2];
  const float* wout = (const float*)d_in[3];
  const float* bout = (const float*)d_in[4];
  float* out = (float*)d_out;
  char* ws = (char*)d_ws;

  _Float16* wt16   = (_Float16*)(ws + 0);          //    786,432 B
  _Float16* q16    = (_Float16*)(ws + 786432);     // 33,554,432 B
  _Float16* part16 = (_Float16*)(ws + 34340864);   // 33,554,432 B
  float*    dots   = (float*)   (ws + 67895296);   //    524,288 B
  _Float16* wdt    = (_Float16*)(ws + 68419584);   //  1,048,576 B (end 69,468,160)

  k_cvt_w<<<1536, 256, 0, stream>>>(wqkv, wt16);
  k_qkv<<<512, 256, 0, stream>>>(x, wt16, pos, q16, part16);
  k_pred<<<256, 256, 0, stream>>>(part16, dots);
  k_wd<<<dim3(32, 4), 256, 0, stream>>>(dots, wout, wdt);
  k_out<<<512, 256, 0, stream>>>(q16, wdt, bout, out);
}